// Round 5
// baseline (619.909 us; speedup 1.0000x reference)
//
#include <hip/hip_runtime.h>
#include <hip/hip_bf16.h>
#include <math.h>

// Problem constants
constexpr int B  = 128;
constexpr int S  = 128;
constexpr int H  = 1024;
constexpr int E  = 512;
constexpr int V  = 32000;
constexpr int H2 = 2 * H;     // 2048
constexpr int G4 = 4 * H;     // 4096
constexpr int KX = E + H;     // 1536
constexpr int KG = KX + H;    // 2560
constexpr int BS = B * S;     // 16384
constexpr int KSPLIT = 4;
constexpr int KSEG = KG / KSPLIT;  // 640
constexpr int QSPLIT = 4;
constexpr int QSEG = H / QSPLIT;   // 256

typedef float  f32x4  __attribute__((ext_vector_type(4)));
typedef short  short8 __attribute__((ext_vector_type(8)));

// counted-vmcnt single-barrier ring (T3/T4): order per iter is
//   vmcnt((PF-2)*L) ; s_barrier ; stage(k+PF-1) ; compute(k)
// The staged buffer (k+PF-1)%PF == (k-1)%PF was last read in iter k-1;
// every wave past the barrier has finished iter k-1 in program order,
// so ONE barrier per iteration is sufficient for any PF.
#define VMCNT(N) asm volatile("s_waitcnt vmcnt(" #N ")" ::: "memory")
#define SBAR     asm volatile("s_barrier" ::: "memory")
#define SCHED0   __builtin_amdgcn_sched_barrier(0)

// fp32 -> bf16 round-to-nearest-even
__device__ __forceinline__ short f2bf(float f) {
    union { float f; unsigned u; } x; x.f = f;
    unsigned r = (x.u + 0x7FFFu + ((x.u >> 16) & 1u)) >> 16;
    return (short)r;
}
__device__ __forceinline__ float bf2f(unsigned short u) {
    union { unsigned u; float f; } x; x.u = ((unsigned)u) << 16;
    return x.f;
}
__device__ __forceinline__ float fast_tanh(float x) {
    float z = fminf(fmaxf(x, -15.f), 15.f);
    float e = __expf(2.f * z);
    return 1.f - __fdividef(2.f, e + 1.f);
}
__device__ __forceinline__ short8 cvt8(float4 a, float4 b) {
    short8 r;
    r[0] = f2bf(a.x); r[1] = f2bf(a.y); r[2] = f2bf(a.z); r[3] = f2bf(a.w);
    r[4] = f2bf(b.x); r[5] = f2bf(b.y); r[6] = f2bf(b.z); r[7] = f2bf(b.w);
    return r;
}
// async global->LDS, 16B/lane; LDS dest = wave-uniform base + lane*16
__device__ __forceinline__ void glds16(const void* g, void* l) {
    __builtin_amdgcn_global_load_lds(
        (const __attribute__((address_space(1))) unsigned int*)g,
        (__attribute__((address_space(3))) unsigned int*)l,
        16, 0, 0);
}

// ---------------------------------------------------------------------------
// Pure conversion: enc->bf16 (16384 blocks), attn_W[:,H:]->bf16 (1024).
// ---------------------------------------------------------------------------
__global__ __launch_bounds__(256) void k_pre(const float* __restrict__ enc,
                                             short* __restrict__ encb,
                                             const float* __restrict__ attn_W,
                                             short* __restrict__ w2b) {
    int bid = blockIdx.x;
    if (bid < 16384) {
        size_t p = (size_t)bid * 256 + threadIdx.x;
        float4 a = *(const float4*)(enc + p * 4);
        short4 o = { f2bf(a.x), f2bf(a.y), f2bf(a.z), f2bf(a.w) };
        *(short4*)(encb + p * 4) = o;
    } else {
        int p = (bid - 16384) * 256 + threadIdx.x;
        int row = p >> 8;
        int c = (p & 255) * 4;
        float4 a = *(const float4*)(attn_W + (size_t)row * H2 + H + c);
        short4 o = { f2bf(a.x), f2bf(a.y), f2bf(a.z), f2bf(a.w) };
        *(short4*)(w2b + (size_t)row * H + c) = o;
    }
}

// ---------------------------------------------------------------------------
// q MFMA GEMM: qpart[kh][b][n] = hlast[b,:] @ attn_W[n, kh*256:+256]
// PF=2 single-barrier ring, L=5. Grid (32,4).
// ---------------------------------------------------------------------------
__global__ __launch_bounds__(256) void k_q_mfma(const float* __restrict__ hlast,
                                                const float* __restrict__ attn_W,
                                                float* __restrict__ qpart) {
    __shared__ __align__(16) float A_s[2 * 4096];   // 32 KB
    __shared__ __align__(16) float B_s[2 * 1024];   // 8 KB

    const int tid  = threadIdx.x;
    const int wave = tid >> 6, lane = tid & 63;
    const int c16 = lane & 15, q4 = lane >> 4;
    const int n0 = blockIdx.x * 32;
    const int kbeg = blockIdx.y * QSEG;

    const int sc = ((lane & 7) ^ ((lane >> 3) & 7)) * 4;   // float offset
    const int rA = (lane >> 3);
    const int rowB = wave * 8 + (lane >> 3);

    const float* gB = attn_W + (size_t)(n0 + rowB) * H2 + sc;

    auto stage = [&](int k0, int buf) {
#pragma unroll
        for (int j = 0; j < 4; j++) {
            int row = wave * 32 + j * 8 + rA;
            glds16(hlast + (size_t)row * H + k0 + sc,
                   A_s + buf * 4096 + wave * 1024 + j * 256);
        }
        glds16(gB + k0, B_s + buf * 1024 + wave * 256);
    };

    f32x4 acc[2][2] = {};
    stage(kbeg, 0);

    for (int kk = 0; kk < QSEG / 32; kk++) {
        VMCNT(0);
        SCHED0; SBAR; SCHED0;
        if (kk + 1 < QSEG / 32) stage(kbeg + (kk + 1) * 32, (kk + 1) & 1);

        const int abo = (kk & 1) << 12;
        const int bbo = (kk & 1) << 10;
        short8 a[2], bfr[2];
#pragma unroll
        for (int i = 0; i < 2; i++) {
            int ar = wave * 32 + i * 16 + c16;
            int cl = (2 * q4) ^ (ar & 7);
            float4 lo = *(const float4*)(A_s + abo + ar * 32 + cl * 4);
            float4 hi = *(const float4*)(A_s + abo + ar * 32 + (cl ^ 1) * 4);
            a[i] = cvt8(lo, hi);
        }
#pragma unroll
        for (int j = 0; j < 2; j++) {
            int rb = j * 16 + c16;
            int cl = (2 * q4) ^ (rb & 7);
            float4 lo = *(const float4*)(B_s + bbo + rb * 32 + cl * 4);
            float4 hi = *(const float4*)(B_s + bbo + rb * 32 + (cl ^ 1) * 4);
            bfr[j] = cvt8(lo, hi);
        }
#pragma unroll
        for (int i = 0; i < 2; i++)
#pragma unroll
            for (int j = 0; j < 2; j++)
                acc[i][j] = __builtin_amdgcn_mfma_f32_16x16x32_bf16(a[i], bfr[j], acc[i][j], 0, 0, 0);
    }

    float* qp = qpart + (size_t)blockIdx.y * B * H;
#pragma unroll
    for (int i = 0; i < 2; i++)
#pragma unroll
        for (int j = 0; j < 2; j++)
#pragma unroll
            for (int r = 0; r < 4; r++) {
                int R = wave * 32 + i * 16 + q4 * 4 + r;
                int n = n0 + j * 16 + c16;
                qp[(size_t)R * H + n] = acc[i][j][r];
            }
}

// ---------------------------------------------------------------------------
// Energy MFMA GEMM + fused tanh/v/row-reduce.
// PF=3 single-barrier ring, L=4 (steady vmcnt(4)): prefetch distance 2
// covers L3 latency; barrier count halved. LDS 48 KB (3 blocks/CU);
// red[] aliases the ring (fenced by __syncthreads after the loop).
// ---------------------------------------------------------------------------
__global__ __launch_bounds__(256) void k_energy_mfma(const short* __restrict__ encb,
                                                     const short* __restrict__ w2b,
                                                     const float* __restrict__ qpart,
                                                     const float* __restrict__ attn_b,
                                                     const float* __restrict__ v,
                                                     float* __restrict__ part) {
    __shared__ __align__(16) char smem[49152];
    short* Af = (short*)smem;                 // 3 bufs x 4096 shorts = 24 KB
    short* Bf = (short*)(smem + 24576);       // 24 KB
    float (*red)[33] = (float(*)[33])smem;    // 16.9 KB, aliases ring

    const int tid  = threadIdx.x;
    const int wave = tid >> 6, lane = tid & 63;
    const int wr = wave >> 1, wc = wave & 1;
    const int c16 = lane & 15, q4 = lane >> 4;
    const int m0 = blockIdx.x * 128;
    const int n0 = blockIdx.y * 128;

    f32x4 acc[4][4] = {};

    const int scA   = ((lane & 3) ^ ((lane >> 3) & 3)) * 8;   // src short-ofs
    const int rowA0 = wave * 32 + (lane >> 2);
    const int rowA1 = rowA0 + 16;
    const int sa    = (c16 >> 1) & 3;                          // read swizzle

    const short* gA = encb + (size_t)m0 * H;
    const short* gB = w2b + (size_t)n0 * H;

    auto stage = [&](int k0, int buf) {
        glds16(gA + (size_t)rowA0 * H + k0 + scA, Af + buf * 4096 + wave * 1024);
        glds16(gA + (size_t)rowA1 * H + k0 + scA, Af + buf * 4096 + wave * 1024 + 512);
        glds16(gB + (size_t)rowA0 * H + k0 + scA, Bf + buf * 4096 + wave * 1024);
        glds16(gB + (size_t)rowA1 * H + k0 + scA, Bf + buf * 4096 + wave * 1024 + 512);
    };

    stage(0, 0);
    stage(32, 1);

    for (int kk = 0; kk < 32; kk++) {
        if (kk < 31) { VMCNT(4); } else { VMCNT(0); }
        SCHED0; SBAR; SCHED0;
        if (kk + 2 < 32) stage((kk + 2) * 32, (kk + 2) % 3);

        const int bo = (kk % 3) * 4096;
        short8 a[4], b[4];
#pragma unroll
        for (int i = 0; i < 4; i++) {
            int r = wr * 64 + i * 16 + c16;
            a[i] = *(const short8*)(Af + bo + r * 32 + (q4 ^ sa) * 8);
        }
#pragma unroll
        for (int j = 0; j < 4; j++) {
            int r = wc * 64 + j * 16 + c16;
            b[j] = *(const short8*)(Bf + bo + r * 32 + (q4 ^ sa) * 8);
        }
#pragma unroll
        for (int i = 0; i < 4; i++)
#pragma unroll
            for (int j = 0; j < 4; j++)
                acc[i][j] = __builtin_amdgcn_mfma_f32_16x16x32_bf16(a[i], b[j], acc[i][j], 0, 0, 0);
    }
    __syncthreads();   // all tile reads done before red[] overwrites the ring

    const int bb = blockIdx.x;          // b == blockIdx.x (BM==S)
    float qv[4], vv[4];
#pragma unroll
    for (int j = 0; j < 4; j++) {
        int n = n0 + wc * 64 + j * 16 + c16;
        float s = attn_b[n];
#pragma unroll
        for (int kh = 0; kh < QSPLIT; kh++)
            s += qpart[((size_t)kh * B + bb) * H + n];
        qv[j] = s;
        vv[j] = v[n];
    }

#pragma unroll
    for (int i = 0; i < 4; i++) {
#pragma unroll
        for (int r = 0; r < 4; r++) {
            float s = 0.f;
#pragma unroll
            for (int j = 0; j < 4; j++)
                s += vv[j] * fast_tanh(qv[j] + acc[i][j][r]);
            red[wr * 64 + i * 16 + q4 * 4 + r][wc * 16 + c16] = s;
        }
    }
    __syncthreads();
    if (tid < 128) {
        float s = 0.f;
#pragma unroll
        for (int c = 0; c < 32; c++) s += red[tid][c];
        part[(size_t)(m0 + tid) * 8 + blockIdx.y] = s;
    }
}

// ---------------------------------------------------------------------------
// Softmax over S + context, fused with xin packing (4 chunks per b).
// ---------------------------------------------------------------------------
__global__ __launch_bounds__(256) void k_softmax_ctx(const float* __restrict__ part,
                                                     const short* __restrict__ encb,
                                                     const int* __restrict__ x,
                                                     const float* __restrict__ emb,
                                                     const float* __restrict__ hlast,
                                                     float* __restrict__ attn_out,
                                                     short* __restrict__ xinb) {
    const int bid = blockIdx.x;
    const int b = bid >> 2, ch = bid & 3;
    const int tid = threadIdx.x;
    __shared__ float w[S];
    __shared__ float red[128];

    float val = 0.f;
    if (tid < S) {
        const float* p = part + (size_t)(b * S + tid) * 8;
#pragma unroll
        for (int t = 0; t < 8; t++) val += p[t];
        w[tid] = val;
        red[tid] = val;
    }
    __syncthreads();
#pragma unroll
    for (int s = 64; s > 0; s >>= 1) {
        if (tid < s) red[tid] = fmaxf(red[tid], red[tid + s]);
        __syncthreads();
    }
    float m = red[0];
    __syncthreads();
    if (tid < S) { val = __expf(w[tid] - m); red[tid] = val; }
    __syncthreads();
#pragma unroll
    for (int s = 64; s > 0; s >>= 1) {
        if (tid < s) red[tid] += red[tid + s];
        __syncthreads();
    }
    float inv = 1.f / red[0];
    if (tid < S) {
        val *= inv;
        w[tid] = val;
        if (ch == 0) attn_out[b * S + tid] = val;
    }
    if (ch == 1) {
        int xv = x[b];
        float2 e2 = *(const float2*)(emb + (size_t)xv * E + tid * 2);
        short2 eo = { f2bf(e2.x), f2bf(e2.y) };
        *(short2*)(xinb + (size_t)b * KG + tid * 2) = eo;
    } else if (ch == 2) {
        float4 h4 = *(const float4*)(hlast + (size_t)b * H + tid * 4);
        short4 ho = { f2bf(h4.x), f2bf(h4.y), f2bf(h4.z), f2bf(h4.w) };
        *(short4*)(xinb + (size_t)b * KG + KX + tid * 4) = ho;
    }
    __syncthreads();

    const int h = ch * 256 + tid;
    const unsigned short* e = (const unsigned short*)encb + (size_t)b * S * H + h;
    float a0 = 0.f;
#pragma unroll 8
    for (int s = 0; s < S; s++) a0 += w[s] * bf2f(e[(size_t)s * H]);
    xinb[(size_t)b * KG + E + h] = f2bf(a0);
}

// ---------------------------------------------------------------------------
// Gates GEMM: M=128, BN=32, BK=32, K-split 4 (grid 128x4).
// PF=4 single-barrier ring, L=3 (steady vmcnt(6), tail 3/0). LDS 48 KB.
// ---------------------------------------------------------------------------
__global__ __launch_bounds__(256) void k_gates_mfma(const short* __restrict__ xinb,
                                                    const float* __restrict__ W_ih,
                                                    const float* __restrict__ W_hh,
                                                    float* __restrict__ gpart) {
    __shared__ __align__(16) short A_s[4 * 4096];   // 32 KB
    __shared__ __align__(16) float B_s[4 * 1024];   // 16 KB

    const int tid  = threadIdx.x;
    const int wave = tid >> 6, lane = tid & 63;
    const int c16 = lane & 15, q4 = lane >> 4;
    const int n0 = blockIdx.x * 32;
    const int kbeg = blockIdx.y * KSEG;
    constexpr int NIT = KSEG / 32;   // 20

    const int scA   = ((lane & 3) ^ ((lane >> 3) & 3)) * 8;
    const int rowA0 = wave * 32 + (lane >> 2);
    const int rowA1 = rowA0 + 16;
    const int rowB  = wave * 8 + (lane >> 3);
    const int scB   = ((lane & 7) ^ ((lane >> 3) & 7)) * 4;
    const int sa = (c16 >> 1) & 3;
    const int sb = c16 & 7;

    const short* gA0 = xinb + (size_t)rowA0 * KG + scA;
    const short* gA1 = xinb + (size_t)rowA1 * KG + scA;
    const int nr = n0 + rowB;

    auto bsrc = [&](int k0) -> const float* {
        return (k0 < KX) ? (W_ih + (size_t)nr * KX + k0 + scB)
                         : (W_hh + (size_t)nr * H + (k0 - KX) + scB);
    };
    auto stage = [&](int k0, int buf) {
        glds16(gA0 + k0, A_s + buf * 4096 + wave * 1024);
        glds16(gA1 + k0, A_s + buf * 4096 + wave * 1024 + 512);
        glds16(bsrc(k0), B_s + buf * 1024 + wave * 256);
    };

    f32x4 acc[2][2] = {};
    stage(kbeg, 0);
    stage(kbeg + 32, 1);
    stage(kbeg + 64, 2);

    for (int kk = 0; kk < NIT; kk++) {
        if (kk < NIT - 2)      { VMCNT(6); }
        else if (kk == NIT - 2){ VMCNT(3); }
        else                   { VMCNT(0); }
        SCHED0; SBAR; SCHED0;
        if (kk + 3 < NIT) stage(kbeg + (kk + 3) * 32, (kk + 3) & 3);

        const int abo = (kk & 3) << 12;
        const int bbo = (kk & 3) << 10;
        short8 a[2], bfr[2];
#pragma unroll
        for (int i = 0; i < 2; i++) {
            int r = wave * 32 + i * 16 + c16;
            a[i] = *(const short8*)(A_s + abo + r * 32 + (q4 ^ sa) * 8);
        }
#pragma unroll
        for (int j = 0; j < 2; j++) {
            int rb = j * 16 + c16;
            int cl = (2 * q4) ^ sb;
            float4 lo = *(const float4*)(B_s + bbo + rb * 32 + cl * 4);
            float4 hi = *(const float4*)(B_s + bbo + rb * 32 + (cl ^ 1) * 4);
            bfr[j] = cvt8(lo, hi);
        }
#pragma unroll
        for (int i = 0; i < 2; i++)
#pragma unroll
            for (int j = 0; j < 2; j++)
                acc[i][j] = __builtin_amdgcn_mfma_f32_16x16x32_bf16(a[i], bfr[j], acc[i][j], 0, 0, 0);
    }

    float* gp = gpart + (size_t)blockIdx.y * B * G4;
#pragma unroll
    for (int i = 0; i < 2; i++)
#pragma unroll
        for (int j = 0; j < 2; j++)
#pragma unroll
            for (int r = 0; r < 4; r++) {
                int R = wave * 32 + i * 16 + q4 * 4 + r;
                int n = n0 + j * 16 + c16;
                gp[(size_t)R * G4 + n] = acc[i][j][r];
            }
}

// ---------------------------------------------------------------------------
// LSTM pointwise; sums KSPLIT gate partials + biases.
// ---------------------------------------------------------------------------
__global__ __launch_bounds__(256) void k_lstm(const float* __restrict__ gpart,
                                              const float* __restrict__ cell,
                                              const float* __restrict__ b_ih,
                                              const float* __restrict__ b_hh,
                                              const short* __restrict__ xinb,
                                              float* __restrict__ out_h,
                                              float* __restrict__ out_c,
                                              short* __restrict__ xoutb) {
    int idx = blockIdx.x * 256 + threadIdx.x;
    int b = idx >> 10;
    int h = idx & (H - 1);
    float ig = b_ih[h]         + b_hh[h];
    float fg = b_ih[H + h]     + b_hh[H + h];
    float gg = b_ih[2 * H + h] + b_hh[2 * H + h];
    float og = b_ih[3 * H + h] + b_hh[3 * H + h];
#pragma unroll
    for (int p = 0; p < KSPLIT; p++) {
        const float* g = gpart + ((size_t)p * B + b) * G4;
        ig += g[h]; fg += g[H + h]; gg += g[2 * H + h]; og += g[3 * H + h];
    }
    float si = 1.f / (1.f + expf(-ig));
    float sf = 1.f / (1.f + expf(-fg));
    float so = 1.f / (1.f + expf(-og));
    float c = sf * cell[idx] + si * tanhf(gg);
    float hn = so * tanhf(c);
    out_h[idx] = hn;
    out_c[idx] = c;
    xoutb[(size_t)b * H2 + h] = f2bf(hn);
    xoutb[(size_t)b * H2 + H + h] = xinb[(size_t)b * KG + E + h];
}

// ---------------------------------------------------------------------------
// fc GEMM: M=128 N=32000 K=2048. BM=128, BN=32, BK=32, grid 1000.
// PF=4 single-barrier ring, L=3 (steady vmcnt(6), tail 3/0): prefetch
// distance 3 + ~12 waves/CU of independent streams -> HBM-roofline B stream.
// ---------------------------------------------------------------------------
__global__ __launch_bounds__(256) void k_fc_mfma(const short* __restrict__ xoutb,
                                                 const float* __restrict__ fcW,
                                                 const float* __restrict__ fcb,
                                                 float* __restrict__ logits) {
    __shared__ __align__(16) short A_s[4 * 4096];   // 32 KB
    __shared__ __align__(16) float B_s[4 * 1024];   // 16 KB

    const int tid  = threadIdx.x;
    const int wave = tid >> 6, lane = tid & 63;
    const int c16 = lane & 15, q4 = lane >> 4;
    const int n0 = blockIdx.x * 32;
    constexpr int NIT = H2 / 32;   // 64

    const int scA   = ((lane & 3) ^ ((lane >> 3) & 3)) * 8;
    const int rowA0 = wave * 32 + (lane >> 2);
    const int rowA1 = rowA0 + 16;
    const int rowB  = wave * 8 + (lane >> 3);
    const int scB   = ((lane & 7) ^ ((lane >> 3) & 7)) * 4;
    const int sa = (c16 >> 1) & 3;
    const int sb = c16 & 7;

    const short* gA0 = xoutb + (size_t)rowA0 * H2 + scA;
    const short* gA1 = xoutb + (size_t)rowA1 * H2 + scA;
    const float* gBr = fcW + (size_t)(n0 + rowB) * H2 + scB;

    auto stage = [&](int k0, int buf) {
        glds16(gA0 + k0, A_s + buf * 4096 + wave * 1024);
        glds16(gA1 + k0, A_s + buf * 4096 + wave * 1024 + 512);
        glds16(gBr + k0, B_s + buf * 1024 + wave * 256);
    };

    f32x4 acc[2][2] = {};
    stage(0, 0);
    stage(32, 1);
    stage(64, 2);

    for (int kk = 0; kk < NIT; kk++) {
        if (kk < NIT - 2)      { VMCNT(6); }
        else if (kk == NIT - 2){ VMCNT(3); }
        else                   { VMCNT(0); }
        SCHED0; SBAR; SCHED0;
        if (kk + 3 < NIT) stage((kk + 3) * 32, (kk + 3) & 3);

        const int abo = (kk & 3) << 12;
        const int bbo = (kk & 3) << 10;
        short8 a[2], bfr[2];
#pragma unroll
        for (int i = 0; i < 2; i++) {
            int r = wave * 32 + i * 16 + c16;
            a[i] = *(const short8*)(A_s + abo + r * 32 + (q4 ^ sa) * 8);
        }
#pragma unroll
        for (int j = 0; j < 2; j++) {
            int rb = j * 16 + c16;
            int cl = (2 * q4) ^ sb;
            float4 lo = *(const float4*)(B_s + bbo + rb * 32 + cl * 4);
            float4 hi = *(const float4*)(B_s + bbo + rb * 32 + (cl ^ 1) * 4);
            bfr[j] = cvt8(lo, hi);
        }
#pragma unroll
        for (int i = 0; i < 2; i++)
#pragma unroll
            for (int j = 0; j < 2; j++)
                acc[i][j] = __builtin_amdgcn_mfma_f32_16x16x32_bf16(a[i], bfr[j], acc[i][j], 0, 0, 0);
    }

#pragma unroll
    for (int i = 0; i < 2; i++)
#pragma unroll
        for (int j = 0; j < 2; j++) {
            int n = n0 + j * 16 + c16;
            float bias = fcb[n];
#pragma unroll
            for (int r = 0; r < 4; r++) {
                int R = wave * 32 + i * 16 + q4 * 4 + r;
                logits[(size_t)R * V + n] = acc[i][j][r] + bias;
            }
        }
}

// ---------------------------------------------------------------------------
extern "C" void kernel_launch(void* const* d_in, const int* in_sizes, int n_in,
                              void* d_out, int out_size, void* d_ws, size_t ws_size,
                              hipStream_t stream) {
    const int*   x      = (const int*)d_in[0];
    const float* hidden = (const float*)d_in[1];
    const float* cell   = (const float*)d_in[2];
    const float* enc    = (const float*)d_in[3];
    const float* emb    = (const float*)d_in[4];
    const float* attn_W = (const float*)d_in[5];
    const float* attn_b = (const float*)d_in[6];
    const float* v      = (const float*)d_in[7];
    const float* W_ih   = (const float*)d_in[8];
    const float* W_hh   = (const float*)d_in[9];
    const float* b_ih   = (const float*)d_in[10];
    const float* b_hh   = (const float*)d_in[11];
    const float* fc_W   = (const float*)d_in[12];
    const float* fc_b   = (const float*)d_in[13];

    float* out = (float*)d_out;
    float* logits   = out;                                   // [B,V]
    float* out_h    = out + (size_t)B * V;                   // [1,B,H]
    float* out_c    = out_h + (size_t)B * H;                 // [1,B,H]
    float* out_attn = out_c + (size_t)B * H;                 // [B,S]

    // workspace layout (16B-aligned)
    char* ws = (char*)d_ws;
    short* encb  = (short*)ws;   ws += (size_t)BS * H * 2;   // 33.5 MB
    short* w2b   = (short*)ws;   ws += (size_t)H * H * 2;    // 2 MB
    short* xinb  = (short*)ws;   ws += (size_t)B * KG * 2;   // 0.66 MB
    short* xoutb = (short*)ws;   ws += (size_t)B * H2 * 2;   // 0.5 MB
    float* qpart = (float*)ws;   ws += (size_t)QSPLIT * B * H * 4;  // 2 MB
    float* part  = (float*)ws;   ws += (size_t)BS * 8 * 4;
    float* gpart = (float*)ws;   ws += (size_t)KSPLIT * B * G4 * 4; // 8 MB

    k_q_mfma<<<dim3(H / 32, QSPLIT), dim3(256), 0, stream>>>(hidden, attn_W, qpart);
    k_pre<<<dim3(16384 + 1024), dim3(256), 0, stream>>>(enc, encb, attn_W, w2b);
    k_energy_mfma<<<dim3(BS / 128, H / 128), dim3(256), 0, stream>>>(encb, w2b, qpart,
                                                                     attn_b, v, part);
    k_softmax_ctx<<<dim3(B * 4), dim3(256), 0, stream>>>(part, encb, x, emb, hidden, out_attn, xinb);
    k_gates_mfma<<<dim3(G4 / 32, KSPLIT), dim3(256), 0, stream>>>(xinb, W_ih, W_hh, gpart);
    k_lstm<<<dim3(B * H / 256), dim3(256), 0, stream>>>(gpart, cell, b_ih, b_hh, xinb,
                                                        out_h, out_c, xoutb);
    k_fc_mfma<<<dim3(V / 32), dim3(256), 0, stream>>>(xoutb, fc_W, fc_b, logits);
}